// Round 2
// baseline (137.093 us; speedup 1.0000x reference)
//
#include <hip/hip_runtime.h>
#include <hip/hip_bf16.h>

// ECC / edge-conditioned aggregation, fused:
//   A = relu(edges @ W^T + bias)        [B, N*N, D*D]   (bf16 MFMA, f32 accum)
//   msg[b,i,j,:] = A[b,ij,:,:] @ nodes[b,j,:]
//   out[b,i,:]   = sum_j mask[b,ij] * msg[b,i,j,:]
//
// Decomposition: grid = B*N blocks (one per (b,i)), 256 threads = 4 waves.
// MFMA mapped as M=g(=dout*32+e), N=j, K=f so each 16x16 C-tile is a single
// dout; relu/nodes/mask epilogue is per-lane FMAs, one 64-lane reduction per
// dout at the end. Wave w owns g-tiles [w*16, w*16+16) -> douts [w*8, w*8+8).

#define B_ 16
#define N_ 64
#define D_ 32
#define F_ 32

typedef __attribute__((ext_vector_type(8))) short bf16x8;
typedef __attribute__((ext_vector_type(4))) float f32x4;

__device__ __forceinline__ short f2bf(float x) {
    // round-to-nearest-even f32 -> bf16
    unsigned u = __builtin_bit_cast(unsigned, x);
    u += 0x7fffu + ((u >> 16) & 1u);
    return (short)(u >> 16);
}

__global__ __launch_bounds__(256, 4) void ecc_fused_kernel(
    const float* __restrict__ nodes,  // [16][64][32]
    const float* __restrict__ edges,  // [16][4096][32]
    const float* __restrict__ mask,   // [16][4096]
    const float* __restrict__ W,      // [1024][32]
    const float* __restrict__ bias,   // [1024]
    float* __restrict__ out)          // [16][64][32]
{
    const int tid  = threadIdx.x;
    const int lane = tid & 63;
    const int wv   = tid >> 6;   // wave 0..3
    const int col  = lane & 15;  // MFMA "16-lane" index: A-row(g) / B-col(j) / C-col(j)
    const int grp  = lane >> 4;  // 0..3: K-block for A/B operands, row-group for C
    const int bi   = blockIdx.x; // 0..1023
    const int b    = bi >> 6;
    const int i    = bi & 63;

    const int f0 = grp * 8;      // K offset this lane covers in A/B operands

    // ---- Preload edge B-fragments (bf16), one per j-tile (jt = 0..3).
    // B operand layout: lane holds B[k=f0..f0+7][n=col] = edges[j=jt*16+col][f0..f0+7]
    const float* eb = edges + (b * (N_ * N_) + i * N_) * F_;
    bf16x8 bfrag[4];
#pragma unroll
    for (int jt = 0; jt < 4; ++jt) {
        const float* s = eb + (jt * 16 + col) * F_ + f0;
        f32x4 e0 = *(const f32x4*)s;
        f32x4 e1 = *(const f32x4*)(s + 4);
        bf16x8 t;
        t[0] = f2bf(e0[0]); t[1] = f2bf(e0[1]); t[2] = f2bf(e0[2]); t[3] = f2bf(e0[3]);
        t[4] = f2bf(e1[0]); t[5] = f2bf(e1[1]); t[6] = f2bf(e1[2]); t[7] = f2bf(e1[3]);
        bfrag[jt] = t;
    }

    // ---- Preload mask per j-tile (depends on this lane's C-column j = jt*16+col)
    float mk[4];
    const float* mb = mask + b * (N_ * N_) + i * N_;
#pragma unroll
    for (int jt = 0; jt < 4; ++jt) mk[jt] = mb[jt * 16 + col];

    // ---- Preload nodes: nd[jt][par] = nodes[b][jt*16+col][par*16 + grp*4 .. +3]
    // (C-fragment rows are g = gt*16 + grp*4 + reg -> e = (gt&1)*16 + grp*4 + reg)
    f32x4 nd[4][2];
    const float* nb = nodes + b * N_ * D_;
#pragma unroll
    for (int jt = 0; jt < 4; ++jt)
#pragma unroll
        for (int par = 0; par < 2; ++par)
            nd[jt][par] = *(const f32x4*)(nb + (jt * 16 + col) * D_ + par * 16 + grp * 4);

    float acc[8] = {0.f, 0.f, 0.f, 0.f, 0.f, 0.f, 0.f, 0.f};

#pragma unroll
    for (int gtl = 0; gtl < 16; ++gtl) {
        const int gt = wv * 16 + gtl;  // g-tile index, g in [gt*16, gt*16+16)
        // A operand: lane holds W[g = gt*16+col][f0..f0+7], converted to bf16
        const float* ws = W + (gt * 16 + col) * F_ + f0;
        f32x4 w0 = *(const f32x4*)ws;
        f32x4 w1 = *(const f32x4*)(ws + 4);
        bf16x8 afrag;
        afrag[0] = f2bf(w0[0]); afrag[1] = f2bf(w0[1]);
        afrag[2] = f2bf(w0[2]); afrag[3] = f2bf(w0[3]);
        afrag[4] = f2bf(w1[0]); afrag[5] = f2bf(w1[1]);
        afrag[6] = f2bf(w1[2]); afrag[7] = f2bf(w1[3]);

        // bias as MFMA C-in: bias[g] for this lane's 4 C-rows (g = gt*16+grp*4+reg)
        f32x4 bfr = *(const f32x4*)(bias + gt * 16 + grp * 4);

        const int par = gt & 1;    // e-range half: e = par*16 + grp*4 + reg
        const int dl  = gtl >> 1;  // local dout accumulator (dout = wv*8 + dl)

#pragma unroll
        for (int jt = 0; jt < 4; ++jt) {
            f32x4 c = __builtin_amdgcn_mfma_f32_16x16x32_bf16(afrag, bfrag[jt], bfr, 0, 0, 0);
            f32x4 n = nd[jt][par];
            float s = fmaxf(c[0], 0.f) * n[0];
            s += fmaxf(c[1], 0.f) * n[1];
            s += fmaxf(c[2], 0.f) * n[2];
            s += fmaxf(c[3], 0.f) * n[3];
            acc[dl] += mk[jt] * s;  // mask depends only on j = jt*16+col
        }
    }

    // ---- Full-wave reduction: sum over 16 j-columns x 4 e-groups (64 lanes)
#pragma unroll
    for (int dl = 0; dl < 8; ++dl) {
        float v = acc[dl];
#pragma unroll
        for (int off = 32; off > 0; off >>= 1) v += __shfl_xor(v, off, 64);
        acc[dl] = v;
    }

    if (lane == 0) {
        float* op = out + (b * N_ + i) * D_ + wv * 8;
#pragma unroll
        for (int dl = 0; dl < 8; ++dl) op[dl] = acc[dl];
    }
}

extern "C" void kernel_launch(void* const* d_in, const int* in_sizes, int n_in,
                              void* d_out, int out_size, void* d_ws, size_t ws_size,
                              hipStream_t stream) {
    const float* nodes = (const float*)d_in[0];  // 16*64*32
    const float* edges = (const float*)d_in[1];  // 16*4096*32
    const float* mask  = (const float*)d_in[2];  // 16*4096
    const float* W     = (const float*)d_in[3];  // 1024*32
    const float* bias  = (const float*)d_in[4];  // 1024
    float* outp        = (float*)d_out;          // 16*64*32

    ecc_fused_kernel<<<dim3(B_ * N_), dim3(256), 0, stream>>>(
        nodes, edges, mask, W, bias, outp);
}

// Round 11
// 133.980 us; speedup vs baseline: 1.0232x; 1.0232x over previous
//
#include <hip/hip_runtime.h>
#include <hip/hip_bf16.h>

// ECC / edge-conditioned aggregation, fused:
//   A = relu(edges @ W^T + bias)        [B, N*N, D*D]   (bf16 MFMA, f32 accum)
//   msg[b,i,j,:] = A[b,ij,:,:] @ nodes[b,j,:]
//   out[b,i,:]   = sum_j mask[b,ij] * msg[b,i,j,:]
//
// R11 = EXACT R2 kernel body (passed on-device, absmax 0.25, 82us spill-bound)
// with ONE change: __launch_bounds__(256,4) -> __launch_bounds__(256) +
// amdgpu_waves_per_eu(4,4), to pin the VGPR budget at 128 and kill the
// ~850 B/thread scratch spill (R2: WRITE_SIZE 127 MB at VGPR_Count=64).
// Isolation experiment: R6/R10 failed (absmax ~6-7) with this attribute
// plus other edits; R2 passed without it. If R11 fails, the attribute is
// the miscompile; if it passes, the spill fix is in and we tune from there.

#define B_ 16
#define N_ 64
#define D_ 32
#define F_ 32

typedef __attribute__((ext_vector_type(8))) short bf16x8;
typedef __attribute__((ext_vector_type(4))) float f32x4;

__device__ __forceinline__ short f2bf(float x) {
    // round-to-nearest-even f32 -> bf16
    unsigned u = __builtin_bit_cast(unsigned, x);
    u += 0x7fffu + ((u >> 16) & 1u);
    return (short)(u >> 16);
}

__global__
__launch_bounds__(256)
__attribute__((amdgpu_waves_per_eu(4, 4)))
void ecc_fused_kernel(
    const float* __restrict__ nodes,  // [16][64][32]
    const float* __restrict__ edges,  // [16][4096][32]
    const float* __restrict__ mask,   // [16][4096]
    const float* __restrict__ W,      // [1024][32]
    const float* __restrict__ bias,   // [1024]
    float* __restrict__ out)          // [16][64][32]
{
    const int tid  = threadIdx.x;
    const int lane = tid & 63;
    const int wv   = tid >> 6;   // wave 0..3
    const int col  = lane & 15;  // MFMA "16-lane" index: A-row(g) / B-col(j) / C-col(j)
    const int grp  = lane >> 4;  // 0..3: K-block for A/B operands, row-group for C
    const int bi   = blockIdx.x; // 0..1023
    const int b    = bi >> 6;
    const int i    = bi & 63;

    const int f0 = grp * 8;      // K offset this lane covers in A/B operands

    // ---- Preload edge B-fragments (bf16), one per j-tile (jt = 0..3).
    // B operand layout: lane holds B[k=f0..f0+7][n=col] = edges[j=jt*16+col][f0..f0+7]
    const float* eb = edges + (b * (N_ * N_) + i * N_) * F_;
    bf16x8 bfrag[4];
#pragma unroll
    for (int jt = 0; jt < 4; ++jt) {
        const float* s = eb + (jt * 16 + col) * F_ + f0;
        f32x4 e0 = *(const f32x4*)s;
        f32x4 e1 = *(const f32x4*)(s + 4);
        bf16x8 t;
        t[0] = f2bf(e0[0]); t[1] = f2bf(e0[1]); t[2] = f2bf(e0[2]); t[3] = f2bf(e0[3]);
        t[4] = f2bf(e1[0]); t[5] = f2bf(e1[1]); t[6] = f2bf(e1[2]); t[7] = f2bf(e1[3]);
        bfrag[jt] = t;
    }

    // ---- Preload mask per j-tile (depends on this lane's C-column j = jt*16+col)
    float mk[4];
    const float* mb = mask + b * (N_ * N_) + i * N_;
#pragma unroll
    for (int jt = 0; jt < 4; ++jt) mk[jt] = mb[jt * 16 + col];

    // ---- Preload nodes: nd[jt][par] = nodes[b][jt*16+col][par*16 + grp*4 .. +3]
    // (C-fragment rows are g = gt*16 + grp*4 + reg -> e = (gt&1)*16 + grp*4 + reg)
    f32x4 nd[4][2];
    const float* nb = nodes + b * N_ * D_;
#pragma unroll
    for (int jt = 0; jt < 4; ++jt)
#pragma unroll
        for (int par = 0; par < 2; ++par)
            nd[jt][par] = *(const f32x4*)(nb + (jt * 16 + col) * D_ + par * 16 + grp * 4);

    float acc[8] = {0.f, 0.f, 0.f, 0.f, 0.f, 0.f, 0.f, 0.f};

#pragma unroll
    for (int gtl = 0; gtl < 16; ++gtl) {
        const int gt = wv * 16 + gtl;  // g-tile index, g in [gt*16, gt*16+16)
        // A operand: lane holds W[g = gt*16+col][f0..f0+7], converted to bf16
        const float* ws = W + (gt * 16 + col) * F_ + f0;
        f32x4 w0 = *(const f32x4*)ws;
        f32x4 w1 = *(const f32x4*)(ws + 4);
        bf16x8 afrag;
        afrag[0] = f2bf(w0[0]); afrag[1] = f2bf(w0[1]);
        afrag[2] = f2bf(w0[2]); afrag[3] = f2bf(w0[3]);
        afrag[4] = f2bf(w1[0]); afrag[5] = f2bf(w1[1]);
        afrag[6] = f2bf(w1[2]); afrag[7] = f2bf(w1[3]);

        // bias as MFMA C-in: bias[g] for this lane's 4 C-rows (g = gt*16+grp*4+reg)
        f32x4 bfr = *(const f32x4*)(bias + gt * 16 + grp * 4);

        const int par = gt & 1;    // e-range half: e = par*16 + grp*4 + reg
        const int dl  = gtl >> 1;  // local dout accumulator (dout = wv*8 + dl)

#pragma unroll
        for (int jt = 0; jt < 4; ++jt) {
            f32x4 c = __builtin_amdgcn_mfma_f32_16x16x32_bf16(afrag, bfrag[jt], bfr, 0, 0, 0);
            f32x4 n = nd[jt][par];
            float s = fmaxf(c[0], 0.f) * n[0];
            s += fmaxf(c[1], 0.f) * n[1];
            s += fmaxf(c[2], 0.f) * n[2];
            s += fmaxf(c[3], 0.f) * n[3];
            acc[dl] += mk[jt] * s;  // mask depends only on j = jt*16+col
        }
    }

    // ---- Full-wave reduction: sum over 16 j-columns x 4 e-groups (64 lanes)
#pragma unroll
    for (int dl = 0; dl < 8; ++dl) {
        float v = acc[dl];
#pragma unroll
        for (int off = 32; off > 0; off >>= 1) v += __shfl_xor(v, off, 64);
        acc[dl] = v;
    }

    if (lane == 0) {
        float* op = out + (b * N_ + i) * D_ + wv * 8;
#pragma unroll
        for (int dl = 0; dl < 8; ++dl) op[dl] = acc[dl];
    }
}

extern "C" void kernel_launch(void* const* d_in, const int* in_sizes, int n_in,
                              void* d_out, int out_size, void* d_ws, size_t ws_size,
                              hipStream_t stream) {
    const float* nodes = (const float*)d_in[0];  // 16*64*32
    const float* edges = (const float*)d_in[1];  // 16*4096*32
    const float* mask  = (const float*)d_in[2];  // 16*4096
    const float* W     = (const float*)d_in[3];  // 1024*32
    const float* bias  = (const float*)d_in[4];  // 1024
    float* outp        = (float*)d_out;          // 16*64*32

    ecc_fused_kernel<<<dim3(B_ * N_), dim3(256), 0, stream>>>(
        nodes, edges, mask, W, bias, outp);
}

// Round 17
// 105.145 us; speedup vs baseline: 1.3039x; 1.2742x over previous
//
#include <hip/hip_runtime.h>
#include <hip/hip_bf16.h>

// ECC / edge-conditioned aggregation, fused single kernel:
//   A = relu(edges @ W^T + bias)        [B, N*N, D*D]   (bf16 MFMA, f32 accum)
//   out[b,i,:] = sum_j mask[b,ij] * (A[b,ij,:,:] @ nodes[b,j,:])
//
// Grid = B*N blocks (one per (b,i)), 256 threads = 4 waves. MFMA M=g, N=j,
// K=f; each 16x16 C-tile is one dout. Epilogue relu+fma per lane, one
// 64-lane reduction per dout.
//
// History: R2/R11 passed (absmax 0.25) but spilled ~850 B/thread
// (VGPR_Count=64, WRITE_SIZE 127 MB, ~80us) — persistent regs (~60) + W-load
// transients exceed the allocator's 64-VGPR budget, and attributes cannot
// raise it (R11). R15's two-kernel d_ws pipeline corrupted under the
// harness's d_ws re-poisoning — single kernel only.
// R16: fit 64 VGPRs for real: mask-premultiplied nodes live in LDS
// (staged once, 8.4 KB, pad 33 vs bank conflicts); per-par node slice
// hoisted to nd[4][4] (16 regs, reused across 8 g-tiles). Persistent:
// bfrag 16 + nd 16 + acc 8 + bases ~8 = ~48 < 64 -> no spill.

#define B_ 16
#define N_ 64
#define D_ 32
#define F_ 32
#define NP 33  // LDS row stride (pad +1: breaks power-of-2 bank aliasing)

typedef __attribute__((ext_vector_type(8))) short bf16x8;
typedef __attribute__((ext_vector_type(4))) float f32x4;

__device__ __forceinline__ short f2bf(float x) {
    // round-to-nearest-even f32 -> bf16 (proven R2/R11: absmax 0.25)
    unsigned u = __builtin_bit_cast(unsigned, x);
    u += 0x7fffu + ((u >> 16) & 1u);
    return (short)(u >> 16);
}

__global__ __launch_bounds__(256, 4) void ecc_fused_kernel(
    const float* __restrict__ nodes,  // [16][64][32]
    const float* __restrict__ edges,  // [16][4096][32]
    const float* __restrict__ mask,   // [16][4096]
    const float* __restrict__ W,      // [1024][32]
    const float* __restrict__ bias,   // [1024]
    float* __restrict__ out)          // [16][64][32]
{
    __shared__ float nmask[N_ * NP];  // nmask[j][e] = mask[b,i*64+j]*nodes[b,j,e]

    const int tid  = threadIdx.x;
    const int lane = tid & 63;
    const int wv   = tid >> 6;   // wave 0..3
    const int col  = lane & 15;  // MFMA 16-index: A-row(g) / B-col(j) / C-col(j)
    const int grp  = lane >> 4;  // 0..3: K-block for A/B, row-group for C
    const int bi   = blockIdx.x; // 0..1023
    const int b    = bi >> 6;
    const int i    = bi & 63;
    const int f0   = grp * 8;    // K offset this lane covers in A/B operands

    // ---- Stage mask-premultiplied nodes into LDS (once; mask is exactly 0/1)
    {
        const int j  = tid >> 2;        // 0..63
        const int c0 = (tid & 3) * 8;   // 0,8,16,24
        const float mk = mask[b * (N_ * N_) + i * N_ + j];
        const float* np = nodes + (b * N_ + j) * D_ + c0;
        f32x4 v0 = *(const f32x4*)np;
        f32x4 v1 = *(const f32x4*)(np + 4);
        float* dst = &nmask[j * NP + c0];
        dst[0] = v0[0] * mk; dst[1] = v0[1] * mk;
        dst[2] = v0[2] * mk; dst[3] = v0[3] * mk;
        dst[4] = v1[0] * mk; dst[5] = v1[1] * mk;
        dst[6] = v1[2] * mk; dst[7] = v1[3] * mk;
    }
    __syncthreads();

    // ---- Edge B-fragments (bf16), one per j-tile; converted once.
    // lane holds B[k=f0..f0+7][n=col] = edges[j=jt*16+col][f0..f0+7]
    const float* eb = edges + (b * (N_ * N_) + i * N_) * F_;
    bf16x8 bfrag[4];
#pragma unroll
    for (int jt = 0; jt < 4; ++jt) {
        const float* s = eb + (jt * 16 + col) * F_ + f0;
        f32x4 e0 = *(const f32x4*)s;
        f32x4 e1 = *(const f32x4*)(s + 4);
        bf16x8 t;
        t[0] = f2bf(e0[0]); t[1] = f2bf(e0[1]); t[2] = f2bf(e0[2]); t[3] = f2bf(e0[3]);
        t[4] = f2bf(e1[0]); t[5] = f2bf(e1[1]); t[6] = f2bf(e1[2]); t[7] = f2bf(e1[3]);
        bfrag[jt] = t;
    }

    float acc[8] = {0.f, 0.f, 0.f, 0.f, 0.f, 0.f, 0.f, 0.f};

    // C-fragment rows: g = gt*16 + grp*4 + reg, e = (gt&1)*16 + grp*4 + reg.
    // Split gt by parity so the node slice for one e-half is register-hoisted
    // (16 regs) and reused across 8 g-tiles -> LDS read traffic /8.
#pragma unroll 1
    for (int par = 0; par < 2; ++par) {
        float nd[4][4];
#pragma unroll
        for (int jt = 0; jt < 4; ++jt) {
            const float* n = &nmask[(jt * 16 + col) * NP + par * 16 + grp * 4];
            nd[jt][0] = n[0]; nd[jt][1] = n[1];
            nd[jt][2] = n[2]; nd[jt][3] = n[3];
        }
#pragma unroll
        for (int g8 = 0; g8 < 8; ++g8) {      // static acc index (rule #20)
            const int gt = wv * 16 + g8 * 2 + par;
            const float* ws = W + (gt * 16 + col) * F_ + f0;
            f32x4 w0 = *(const f32x4*)ws;
            f32x4 w1 = *(const f32x4*)(ws + 4);
            bf16x8 afrag;
            afrag[0] = f2bf(w0[0]); afrag[1] = f2bf(w0[1]);
            afrag[2] = f2bf(w0[2]); afrag[3] = f2bf(w0[3]);
            afrag[4] = f2bf(w1[0]); afrag[5] = f2bf(w1[1]);
            afrag[6] = f2bf(w1[2]); afrag[7] = f2bf(w1[3]);

            // bias as MFMA C-in: bias[g], g = gt*16 + grp*4 + reg
            f32x4 bfr = *(const f32x4*)(bias + gt * 16 + grp * 4);

#pragma unroll
            for (int jt = 0; jt < 4; ++jt) {
                f32x4 c = __builtin_amdgcn_mfma_f32_16x16x32_bf16(afrag, bfrag[jt], bfr, 0, 0, 0);
                float s = fmaxf(c[0], 0.f) * nd[jt][0];
                s += fmaxf(c[1], 0.f) * nd[jt][1];
                s += fmaxf(c[2], 0.f) * nd[jt][2];
                s += fmaxf(c[3], 0.f) * nd[jt][3];
                acc[g8] += s;   // dout = wv*8 + g8 (both par halves accumulate)
            }
        }
    }

    // ---- Full-wave reduction: sum over 16 j-columns x 4 e-groups (64 lanes)
#pragma unroll
    for (int dl = 0; dl < 8; ++dl) {
        float v = acc[dl];
#pragma unroll
        for (int off = 32; off > 0; off >>= 1) v += __shfl_xor(v, off, 64);
        acc[dl] = v;
    }

    if (lane == 0) {
        float* op = out + (b * N_ + i) * D_ + wv * 8;
#pragma unroll
        for (int dl = 0; dl < 8; ++dl) op[dl] = acc[dl];
    }
}

extern "C" void kernel_launch(void* const* d_in, const int* in_sizes, int n_in,
                              void* d_out, int out_size, void* d_ws, size_t ws_size,
                              hipStream_t stream) {
    const float* nodes = (const float*)d_in[0];  // 16*64*32
    const float* edges = (const float*)d_in[1];  // 16*4096*32
    const float* mask  = (const float*)d_in[2];  // 16*4096
    const float* W     = (const float*)d_in[3];  // 1024*32
    const float* bias  = (const float*)d_in[4];  // 1024
    float* outp        = (float*)d_out;          // 16*64*32

    ecc_fused_kernel<<<dim3(B_ * N_), dim3(256), 0, stream>>>(
        nodes, edges, mask, W, bias, outp);
}

// Round 18
// 86.749 us; speedup vs baseline: 1.5803x; 1.2121x over previous
//
#include <hip/hip_runtime.h>
#include <hip/hip_bf16.h>

// ECC / edge-conditioned aggregation, fused single kernel:
//   A = relu(edges @ W^T + bias)   [B,N*N,D*D] (bf16 MFMA, f32 accum)
//   out[b,i,:] = sum_j mask[b,ij] * (A[b,ij,:,:] @ nodes[b,j,:])
//
// Grid = B*N blocks (one per (b,i)), 256 threads = 4 waves. MFMA M=g, N=j,
// K=f; each 16x16 C-tile is one dout (dout = wv*8+g8; e = par*16+grp*4+reg).
//
// R18: R17 still spilled ~290 B/thread (WRITE_SIZE 75.9 MB at VGPR=64) —
// in-loop W f32 loads + f2bf converts were the transient pressure. Fix:
// stage W as bf16 in LDS, PAR-SPLIT (only the 512 rows the current par
// phase needs = 32 KB, restaged once), plus bias in LDS (4 KB). Inner loop
// is ds_read_b128 + MFMA only; transients ~8 regs -> fits the 64-VGPR
// budget the allocator insists on (R11: attributes can't raise it).
// Single kernel, no d_ws (R15: ws re-poisoning corrupts chained kernels).

#define B_ 16
#define N_ 64
#define D_ 32
#define F_ 32
#define NP 33  // nmask row stride (pad: scalar reads, negligible conflicts)

typedef __attribute__((ext_vector_type(8))) short bf16x8;
typedef __attribute__((ext_vector_type(4))) float f32x4;

__device__ __forceinline__ short f2bf(float x) {
    // round-to-nearest-even f32 -> bf16 (proven R2/R11/R17: absmax 0.25)
    unsigned u = __builtin_bit_cast(unsigned, x);
    u += 0x7fffu + ((u >> 16) & 1u);
    return (short)(u >> 16);
}

__global__ __launch_bounds__(256) void ecc_fused_kernel(
    const float* __restrict__ nodes,  // [16][64][32]
    const float* __restrict__ edges,  // [16][4096][32]
    const float* __restrict__ mask,   // [16][4096]
    const float* __restrict__ W,      // [1024][32]
    const float* __restrict__ bias,   // [1024]
    float* __restrict__ out)          // [16][64][32]
{
    __shared__ short wlds[512 * F_];  // 32 KB: bf16 W rows for current par
    __shared__ float nmask[N_ * NP];  // 8448 B: mask*nodes
    __shared__ float blds[D_ * D_];   // 4 KB: bias

    const int tid  = threadIdx.x;
    const int lane = tid & 63;
    const int wv   = tid >> 6;   // wave 0..3
    const int col  = lane & 15;  // MFMA 16-index: A-row(g) / B-col(j) / C-col(j)
    const int grp  = lane >> 4;  // 0..3: K-block for A/B, row-group for C
    const int bi   = blockIdx.x; // 0..1023
    const int b    = bi >> 6;
    const int i    = bi & 63;
    const int f0   = grp * 8;    // K offset this lane covers in A/B operands

    // ---- Stage mask-premultiplied nodes (mask is exactly 0/1) + bias
    {
        const int j  = tid >> 2;        // 0..63
        const int c0 = (tid & 3) * 8;   // 0,8,16,24
        const float mk = mask[b * (N_ * N_) + i * N_ + j];
        const float* np = nodes + (b * N_ + j) * D_ + c0;
        f32x4 v0 = *(const f32x4*)np;
        f32x4 v1 = *(const f32x4*)(np + 4);
        float* dst = &nmask[j * NP + c0];
        dst[0] = v0[0] * mk; dst[1] = v0[1] * mk;
        dst[2] = v0[2] * mk; dst[3] = v0[3] * mk;
        dst[4] = v1[0] * mk; dst[5] = v1[1] * mk;
        dst[6] = v1[2] * mk; dst[7] = v1[3] * mk;
        *(f32x4*)(blds + tid * 4) = *(const f32x4*)(bias + tid * 4);
    }

    // ---- Edge B-fragments (bf16), converted once; reused by all 128 MFMAs.
    // lane holds B[k=f0..f0+7][n=col] = edges[j=jt*16+col][f0..f0+7]
    const float* eb = edges + (b * (N_ * N_) + i * N_) * F_;
    bf16x8 bfrag[4];
#pragma unroll
    for (int jt = 0; jt < 4; ++jt) {
        const float* s = eb + (jt * 16 + col) * F_ + f0;
        f32x4 e0 = *(const f32x4*)s;
        f32x4 e1 = *(const f32x4*)(s + 4);
        bf16x8 t;
        t[0] = f2bf(e0[0]); t[1] = f2bf(e0[1]); t[2] = f2bf(e0[2]); t[3] = f2bf(e0[3]);
        t[4] = f2bf(e1[0]); t[5] = f2bf(e1[1]); t[6] = f2bf(e1[2]); t[7] = f2bf(e1[3]);
        bfrag[jt] = t;
    }

    float acc[8] = {0.f, 0.f, 0.f, 0.f, 0.f, 0.f, 0.f, 0.f};

    // g = gt*16 + grp*4 + reg with gt = wv*16 + g8*2 + par;
    // dout = g>>5 = wv*8 + g8 ; e = g&31 = par*16 + grp*4 + reg.
#pragma unroll 1
    for (int par = 0; par < 2; ++par) {
        // par=0: publishes nmask/blds; par=1: waits for all wlds reads of par=0
        __syncthreads();

        // ---- Stage the 512 W rows this par needs, f32 -> bf16.
        // local row lr <-> global row g = ((lr>>4)*2 + par)*16 + (lr&15)
#pragma unroll 2
        for (int k = 0; k < 8; ++k) {
            const int lidx = k * 2048 + tid * 8;  // element index in wlds
            const int lr   = lidx >> 5;           // local row 0..511
            const int fo   = lidx & 31;
            const int g    = (((lr >> 4) * 2 + par) * 16) + (lr & 15);
            const float* s = W + g * F_ + fo;
            f32x4 a0 = *(const f32x4*)s;
            f32x4 a1 = *(const f32x4*)(s + 4);
            bf16x8 t;
            t[0] = f2bf(a0[0]); t[1] = f2bf(a0[1]);
            t[2] = f2bf(a0[2]); t[3] = f2bf(a0[3]);
            t[4] = f2bf(a1[0]); t[5] = f2bf(a1[1]);
            t[6] = f2bf(a1[2]); t[7] = f2bf(a1[3]);
            *(bf16x8*)(wlds + lidx) = t;
        }
        __syncthreads();

        // ---- Node slice for this e-half: 16 regs, reused across 8 g-tiles
        float nd[4][4];
#pragma unroll
        for (int jt = 0; jt < 4; ++jt) {
            const float* n = &nmask[(jt * 16 + col) * NP + par * 16 + grp * 4];
            nd[jt][0] = n[0]; nd[jt][1] = n[1];
            nd[jt][2] = n[2]; nd[jt][3] = n[3];
        }

#pragma unroll 1
        for (int g8 = 0; g8 < 8; ++g8) {       // static acc index (rule #20)
            const int gt   = wv * 16 + g8 * 2 + par;
            const int lrow = (wv * 8 + g8) * 16 + col;  // wlds local row
            // A-fragment straight from LDS (conflict-free: wave reads 1 KB contiguous)
            bf16x8 afrag = *(const bf16x8*)(wlds + lrow * F_ + f0);
            // bias C-in: bias[g], g = gt*16 + grp*4 + reg (broadcast across col)
            f32x4 bfr = *(const f32x4*)(blds + gt * 16 + grp * 4);

#pragma unroll
            for (int jt = 0; jt < 4; ++jt) {
                f32x4 c = __builtin_amdgcn_mfma_f32_16x16x32_bf16(afrag, bfrag[jt], bfr, 0, 0, 0);
                float s = fmaxf(c[0], 0.f) * nd[jt][0];
                s += fmaxf(c[1], 0.f) * nd[jt][1];
                s += fmaxf(c[2], 0.f) * nd[jt][2];
                s += fmaxf(c[3], 0.f) * nd[jt][3];
                acc[g8] += s;   // dout = wv*8 + g8 (both par halves accumulate)
            }
        }
    }

    // ---- Full-wave reduction: sum over 16 j-columns x 4 e-groups (64 lanes)
#pragma unroll
    for (int dl = 0; dl < 8; ++dl) {
        float v = acc[dl];
#pragma unroll
        for (int off = 32; off > 0; off >>= 1) v += __shfl_xor(v, off, 64);
        acc[dl] = v;
    }

    if (lane == 0) {
        float* op = out + (b * N_ + i) * D_ + wv * 8;
#pragma unroll
        for (int dl = 0; dl < 8; ++dl) op[dl] = acc[dl];
    }
}

extern "C" void kernel_launch(void* const* d_in, const int* in_sizes, int n_in,
                              void* d_out, int out_size, void* d_ws, size_t ws_size,
                              hipStream_t stream) {
    const float* nodes = (const float*)d_in[0];  // 16*64*32
    const float* edges = (const float*)d_in[1];  // 16*4096*32
    const float* mask  = (const float*)d_in[2];  // 16*4096
    const float* W     = (const float*)d_in[3];  // 1024*32
    const float* bias  = (const float*)d_in[4];  // 1024
    float* outp        = (float*)d_out;          // 16*64*32

    ecc_fused_kernel<<<dim3(B_ * N_), dim3(256), 0, stream>>>(
        nodes, edges, mask, W, bias, outp);
}